// Round 4
// baseline (138.381 us; speedup 1.0000x reference)
//
#include <hip/hip_runtime.h>
#include <hip/hip_bf16.h>
#include <cstdint>

#define NN    1024
#define FF    64
#define OUTF  128
#define KCAT  192
#define EPSV  1e-6f

typedef __attribute__((ext_vector_type(4))) float  f32x4;
typedef __attribute__((ext_vector_type(8))) __bf16 bf16x8;
typedef __attribute__((ext_vector_type(4))) __bf16 bf16x4;

#define MFMA16(a, b, c) __builtin_amdgcn_mfma_f32_16x16x32_bf16(a, b, c, 0, 0, 0)
#define GLOAD_LDS16(g, l)                                          \
    __builtin_amdgcn_global_load_lds(                              \
        (const __attribute__((address_space(1))) void*)(g),        \
        (__attribute__((address_space(3))) void*)(l), 16, 0, 0)

// ---------------------------------------------------------------------------
// Kernel 1: degree + diag-zero + f32->bf16 conversion of A, fused.
//   Az[b,i,j] = bf16(A[b,i,j] * (i!=j));  deg = 1 + sum_j Az
//   d1 = 1/(eps+deg) ; s = 1/(eps+sqrt(deg))
// One wave per row. 64MB read + 32MB write => BW-bound ~16us.
// ---------------------------------------------------------------------------
__global__ __launch_bounds__(256) void k_deg_cvt(const float* __restrict__ A,
                                                 float* __restrict__ d1,
                                                 float* __restrict__ sArr,
                                                 __bf16* __restrict__ Az) {
    int wave = threadIdx.x >> 6;
    int lane = threadIdx.x & 63;
    int row  = blockIdx.x * 4 + wave;          // [0, 16384)
    int i    = row & (NN - 1);                 // diag index within batch row
    const f32x4* rp = (const f32x4*)(A + (size_t)row * NN);
    __bf16* op = Az + (size_t)row * NN;
    float sum = 0.f;
#pragma unroll
    for (int t = 0; t < 4; ++t) {
        f32x4 v = rp[t * 64 + lane];
        int base = (t * 64 + lane) * 4;
#pragma unroll
        for (int q = 0; q < 4; ++q)
            if (base + q == i) v[q] = 0.f;     // zero diagonal
        sum += v[0] + v[1] + v[2] + v[3];
        bf16x4 o;
#pragma unroll
        for (int q = 0; q < 4; ++q) o[q] = (__bf16)v[q];
        *(bf16x4*)(op + base) = o;
    }
#pragma unroll
    for (int off = 32; off; off >>= 1) sum += __shfl_xor(sum, off);
    if (lane == 0) {
        float deg = 1.0f + sum;
        d1[row]   = 1.0f / (EPSV + deg);
        sArr[row] = 1.0f / (EPSV + sqrtf(deg));
    }
}

// ---------------------------------------------------------------------------
// Kernel 2: K-major bf16 copies of x and s*x, plus transposed bf16 kernel.
//   xT[b][f][n]  = bf16(x[b][n][f]);  sxT[b][f][n] = bf16(s[b][n]*x[b][n][f])
//   KT[c][k]     = bf16(kernel[k][c])        (c<128, k<192)
// ---------------------------------------------------------------------------
__global__ __launch_bounds__(256) void k_prep(const float* __restrict__ x,
                                              const float* __restrict__ sArr,
                                              const float* __restrict__ kern,
                                              __bf16* __restrict__ xT,
                                              __bf16* __restrict__ sxT,
                                              __bf16* __restrict__ KT) {
    __shared__ float tile[64][65];
    int bid = blockIdx.x;                  // 0..255
    int b   = bid >> 4;
    int k0  = (bid & 15) * 64;
    const float* xp = x + ((size_t)b * NN + k0) * FF;
    for (int i = threadIdx.x; i < 64 * 64; i += 256) {
        int r = i >> 6, c = i & 63;
        tile[r][c] = xp[r * FF + c];
    }
    __syncthreads();
    for (int i = threadIdx.x; i < 64 * 64; i += 256) {
        int c = i >> 6, kk = i & 63;
        float v  = tile[kk][c];
        float sv = v * sArr[b * NN + k0 + kk];
        size_t o = ((size_t)b * FF + c) * NN + k0 + kk;
        xT[o]  = (__bf16)v;
        sxT[o] = (__bf16)sv;
    }
    if (threadIdx.x < 96) {
        int idx = bid * 96 + threadIdx.x;
        int c = idx / KCAT;
        int k = idx - c * KCAT;
        KT[idx] = (__bf16)kern[k * OUTF + c];
    }
}

// ---------------------------------------------------------------------------
// Kernel 3: main fused kernel.
// Grid 512 = 16 batches x 32 row-tiles (BM=32), 512 threads (8 waves),
// LDS 64KB -> 2 blocks/CU.
//
// Az panel [32 x 1024] bf16 staged into MFMA-fragment-layout LDS via
// global_load_lds(16B), pre-swizzled per-lane global source, linear dest.
// Fragment layout: off(t,rg,l) = t*2048 + rg*1024 + l*16 holds
// Az[row0 + rg*16 + (l&15)][t*32 + ((l>>4)&3)*8 .. +8].
//
// 2-PHASE PIPELINE: per-thread DMA issue order c = {0,1,4,5,2,3,6,7};
// first 4 issued cover t in [0,8) u [16,24) = first 8 K-steps of BOTH
// wave-halves. Wait vmcnt(4) + raw s_barrier -> compute 8 steps while the
// remaining 32KB streams in -> vmcnt(0) + raw s_barrier -> last 8 steps.
// (NOT __syncthreads: that emits vmcnt(0) and would kill the overlap.)
//
// Wave w = (h = w>>2 K-half, cw = w&3 feature group). Epilogue: cross-half
// LDS reduce, o1/o2/o3 -> bf16 os, then OPERAND-SWAPPED epilogue MFMA
// (D[outcol][osrow]) so each lane owns 4 consecutive out cols ->
// global_store_dwordx4 + vector bias.
// ---------------------------------------------------------------------------
__global__ __launch_bounds__(512, 4) void k_main(const __bf16* __restrict__ Az,
                                                 const float* __restrict__ x,
                                                 const float* __restrict__ bias,
                                                 const float* __restrict__ d1g,
                                                 const float* __restrict__ sg,
                                                 const __bf16* __restrict__ xT,
                                                 const __bf16* __restrict__ sxT,
                                                 const __bf16* __restrict__ KT,
                                                 float* __restrict__ out) {
    __shared__ __align__(16) char smem[65536];   // A-panel / scratch / os

    const int tid  = threadIdx.x;
    const int w    = tid >> 6;
    const int lane = tid & 63;
    const int l15  = lane & 15;
    const int h8   = (lane >> 4) * 8;

    // XCD-chunked swizzle: XCD x runs work ids [x*64, x*64+64) = 2 batches.
    const int work = (blockIdx.x & 7) * 64 + (blockIdx.x >> 3);
    const int b    = work >> 5;
    const int row0 = (work & 31) * 32;

    // ---- stage Az panel into fragment-layout LDS (interleaved chunks) ----
    {
        const __bf16* AzB = Az + (size_t)(b * NN + row0) * NN;
        int rowL = ((tid >> 6) & 1) * 16 + (tid & 15);
        int colB = ((tid >> 7) * 32) + (((tid >> 4) & 3) * 8);
        const __bf16* src = AzB + (size_t)rowL * NN + colB;
        char* ldsb = smem + ((tid >> 6) << 10);     // wave-uniform base
        const int corder[8] = {0, 1, 4, 5, 2, 3, 6, 7};
#pragma unroll
        for (int q = 0; q < 8; ++q) {
            int c = corder[q];
            GLOAD_LDS16(src + c * 128, ldsb + c * 8192);
        }
    }

    const int h  = w >> 2;     // K-half
    const int cw = w & 3;      // feature group

    const __bf16* xP = xT  + ((size_t)(b * FF + cw * 16 + l15)) * NN + h * 512 + h8;
    const __bf16* sP = sxT + ((size_t)(b * FF + cw * 16 + l15)) * NN + h * 512 + h8;
    const char* ldsA = smem + h * 32768 + lane * 16;

    f32x4 P0 = {}, P1 = {}, Q0 = {}, Q1 = {};

#define KSTEP(tt)                                                  \
    {                                                              \
        bf16x8 a0 = *(const bf16x8*)(ldsA + (tt) * 2048);          \
        bf16x8 a1 = *(const bf16x8*)(ldsA + (tt) * 2048 + 1024);   \
        bf16x8 xf = *(const bf16x8*)(xP + (tt) * 32);              \
        bf16x8 sf = *(const bf16x8*)(sP + (tt) * 32);              \
        P0 = MFMA16(a0, xf, P0);                                   \
        P1 = MFMA16(a1, xf, P1);                                   \
        Q0 = MFMA16(a0, sf, Q0);                                   \
        Q1 = MFMA16(a1, sf, Q1);                                   \
    }

    // ---- phase 0: first 4 chunks arrived (t 0..7 / 16..23) ----
    asm volatile("s_waitcnt vmcnt(4)" ::: "memory");
    __builtin_amdgcn_s_barrier();
#pragma unroll
    for (int tt = 0; tt < 8; ++tt) KSTEP(tt)

    // ---- phase 1: remaining chunks ----
    asm volatile("s_waitcnt vmcnt(0)" ::: "memory");
    __builtin_amdgcn_s_barrier();
#pragma unroll
    for (int tt = 8; tt < 16; ++tt) KSTEP(tt)
#undef KSTEP

    // ---- cross-half reduction (h1 -> scratch, h0 adds) --------------------
    __syncthreads();                                    // everyone done with A
    f32x4* sp = (f32x4*)(smem + 32768 + cw * 4096);     // [cw][q][lane] 16B
    if (h == 1) {
        sp[lane]       = P0;
        sp[lane + 64]  = P1;
        sp[lane + 128] = Q0;
        sp[lane + 192] = Q1;
    }
    __syncthreads();
    __bf16 (*os)[208] = (__bf16(*)[208])smem;           // [32][208] = 13.3KB
    if (h == 0) {
        P0 += sp[lane];  P1 += sp[lane + 64];
        Q0 += sp[lane + 128];  Q1 += sp[lane + 192];
#pragma unroll
        for (int rg = 0; rg < 2; ++rg) {
            f32x4 Pv = rg ? P1 : P0;
            f32x4 Qv = rg ? Q1 : Q0;
#pragma unroll
            for (int j = 0; j < 4; ++j) {
                int rr   = rg * 16 + (lane >> 4) * 4 + j;
                int grow = b * NN + row0 + rr;
                float dv = d1g[grow];
                float sv = sg[grow];
                int cc   = cw * 16 + l15;
                float xv = x[(size_t)grow * FF + cc];
                os[rr][cc]        = (__bf16)Pv[j];
                os[rr][64 + cc]   = (__bf16)(dv * (Pv[j] + xv));
                os[rr][128 + cc]  = (__bf16)(sv * (Qv[j] + sv * xv));
            }
        }
    }
    __syncthreads();

    // ---- epilogue GEMM (operand-swapped): D[outcol][osrow] ----------------
    // out[32x128] = relu(os[32x192] @ K[192x128] + bias)
    const int rge = w >> 2;         // row group (0,1)
    const int cg2 = w & 3;          // out col group of 32
    f32x4 e0 = {}, e1 = {};
#pragma unroll
    for (int ks = 0; ks < 6; ++ks) {
        bf16x8 of = *(const bf16x8*)&os[rge * 16 + l15][ks * 32 + h8];
        bf16x8 k0 = *(const bf16x8*)&KT[(size_t)(cg2 * 32 + l15) * KCAT + ks * 32 + h8];
        bf16x8 k1 = *(const bf16x8*)&KT[(size_t)(cg2 * 32 + 16 + l15) * KCAT + ks * 32 + h8];
        e0 = MFMA16(k0, of, e0);    // A = K^T frag, B = os^T frag
        e1 = MFMA16(k1, of, e1);
    }
    // lane holds: osrow = l15, outcols = base + (lane>>4)*4 + j (consecutive)
    {
        const size_t orow = (size_t)(b * NN + row0 + rge * 16 + l15) * OUTF;
#pragma unroll
        for (int g = 0; g < 2; ++g) {
            f32x4 ev = g ? e1 : e0;
            int col0 = cg2 * 32 + g * 16 + (lane >> 4) * 4;
            f32x4 bv = *(const f32x4*)&bias[col0];
            f32x4 r;
#pragma unroll
            for (int j = 0; j < 4; ++j) {
                float v = ev[j] + bv[j];
                r[j] = v > 0.f ? v : 0.f;
            }
            *(f32x4*)&out[orow + col0] = r;
        }
    }
}

// ---------------------------------------------------------------------------
extern "C" void kernel_launch(void* const* d_in, const int* in_sizes, int n_in,
                              void* d_out, int out_size, void* d_ws, size_t ws_size,
                              hipStream_t stream) {
    const float* x    = (const float*)d_in[0];
    const float* A    = (const float*)d_in[1];
    const float* kern = (const float*)d_in[2];
    const float* bias = (const float*)d_in[3];
    float* out = (float*)d_out;

    char* ws = (char*)d_ws;
    __bf16* Az  = (__bf16*)(ws);                                   // 32 MB
    float*  d1  = (float*)(ws + 33554432);                         // 64 KB
    float*  s   = (float*)(ws + 33554432 + 65536);                 // 64 KB
    __bf16* xT  = (__bf16*)(ws + 33554432 + 131072);               // 2 MB
    __bf16* sxT = (__bf16*)(ws + 33554432 + 131072 + 2097152);     // 2 MB
    __bf16* KT  = (__bf16*)(ws + 33554432 + 131072 + 2 * 2097152); // 48 KB
    (void)ws_size; (void)in_sizes; (void)n_in; (void)out_size;

    k_deg_cvt<<<dim3(4096), dim3(256), 0, stream>>>(A, d1, s, Az);
    k_prep<<<dim3(256), dim3(256), 0, stream>>>(x, s, kern, xT, sxT, KT);
    k_main<<<dim3(512), dim3(512), 0, stream>>>(Az, x, bias, d1, s, xT, sxT, KT, out);
}